// Round 7
// baseline (116.760 us; speedup 1.0000x reference)
//
#include <hip/hip_runtime.h>
#include <hip/hip_bf16.h>

// NT-Xent (SimCLR) loss: B=4096, D=128, N=8192, TEMP=0.5.
// Round 7: (a) counted vmcnt that EXCLUDES the epilogue atomics from the
// pipeline wait (was the hidden serial cost: vmcnt(4) drained the 2
// fire-and-forget atomics every tile); (b) T=8 strips (1088 blocks, j-reduce
// amortized 8x); (c) finalize fused into gram via last-block done-counter.

typedef short bfrag __attribute__((ext_vector_type(8)));   // 8 bf16 (4 VGPRs)
typedef float f32x4 __attribute__((ext_vector_type(4)));

static __device__ __forceinline__ unsigned short f2bf_rne(float x) {
    unsigned u = __float_as_uint(x);
    return (unsigned short)((u + 0x7fffu + ((u >> 16) & 1u)) >> 16);
}
static __device__ __forceinline__ float bf2f(unsigned short b) {
    return __uint_as_float(((unsigned)b) << 16);
}

// ------ kernel 1: normalize pair (i, i+B); emit zn/bf16, diag, pos; zero
// sumexp and the gram completion counter (replaces hipMemsetAsync).
__global__ __launch_bounds__(256) void nt_norm_pair(
        const float* __restrict__ zi, const float* __restrict__ zj,
        unsigned short* __restrict__ zn, float* __restrict__ diag,
        float* __restrict__ pos, float* __restrict__ sumexp,
        int* __restrict__ done) {
    constexpr int B = 4096, D = 128;
    const int wave = threadIdx.x >> 6, lane = threadIdx.x & 63;
    const int p = blockIdx.x * 4 + wave;                   // 0..4095
    float2 a = reinterpret_cast<const float2*>(zi + (size_t)p * D)[lane];
    float2 b = reinterpret_cast<const float2*>(zj + (size_t)p * D)[lane];
    float sa = a.x * a.x + a.y * a.y;
    float sb = b.x * b.x + b.y * b.y;
    #pragma unroll
    for (int m = 32; m; m >>= 1) { sa += __shfl_xor(sa, m); sb += __shfl_xor(sb, m); }
    float ia = 1.f / fmaxf(sqrtf(sa), 1e-8f);
    float ib = 1.f / fmaxf(sqrtf(sb), 1e-8f);
    unsigned short a0 = f2bf_rne(a.x * ia), a1 = f2bf_rne(a.y * ia);
    unsigned short b0 = f2bf_rne(b.x * ib), b1 = f2bf_rne(b.y * ib);
    float fa0 = bf2f(a0), fa1 = bf2f(a1), fb0 = bf2f(b0), fb1 = bf2f(b1);
    float da = fa0 * fa0 + fa1 * fa1;                      // bf16 self-dot (matches MFMA diag)
    float db = fb0 * fb0 + fb1 * fb1;
    float cr = fa0 * fb0 + fa1 * fb1;                      // bf16 cross-dot (positive pair)
    #pragma unroll
    for (int m = 32; m; m >>= 1) {
        da += __shfl_xor(da, m); db += __shfl_xor(db, m); cr += __shfl_xor(cr, m);
    }
    reinterpret_cast<unsigned*>(zn + (size_t)p * D)[lane] =
        (unsigned)a0 | ((unsigned)a1 << 16);
    reinterpret_cast<unsigned*>(zn + (size_t)(p + B) * D)[lane] =
        (unsigned)b0 | ((unsigned)b1 << 16);
    if (lane == 0) {
        diag[p] = da; diag[p + B] = db;
        pos[p] = 2.f * cr; pos[p + B] = 2.f * cr;          // sim symmetric
        sumexp[p] = 0.f; sumexp[p + B] = 0.f;
    }
    if (blockIdx.x == 0 && threadIdx.x == 0) *done = 0;
}

// ------ kernel 2: strip-mined symmetric gram + fused finalize --------------
// grid (128, 9): cached tile c = blockIdx.x; y<8: streamed tiles d = 8y+t
// (t=0..7); y==8 (c<64 only): single tile d=64. Each unordered tile pair
// exactly once. acc[fj][fi] = sim[j in cached][i in streamed]. Last block to
// finish runs the scalar finalize.
#define NACTIVE 1088
__global__ __launch_bounds__(256, 4) void nt_gram_sym(
        const unsigned short* __restrict__ zn, float* __restrict__ sumexp,
        const float* __restrict__ diag, const float* __restrict__ pos,
        int* __restrict__ done, float* __restrict__ out) {
    const int c = blockIdx.x;
    const int y = blockIdx.y;
    if (y == 8 && c >= 64) return;
    const int T  = (y == 8) ? 1 : 8;
    const int d0 = (y == 8) ? 64 : 8 * y;

    __shared__ short buf[2][64][128];                      // 2 x 16 KB stream buffers
    __shared__ float red[4];
    __shared__ int lastFlag;

    const short* zs = (const short*)zn;
    const int tid = threadIdx.x, wid = tid >> 6, lane = tid & 63;
    const int wj = wid >> 1, wi = wid & 1;                 // wave quadrant
    const int lr = lane & 15, lk = lane >> 4;

    // cached A-frags (tile c, this wave's 32 j-rows), direct from L2
    bfrag ca[4][2];
    {
        const int rbase = c * 64 + wj * 32;
        #pragma unroll
        for (int ks = 0; ks < 4; ++ks)
            #pragma unroll
            for (int f = 0; f < 2; ++f)
                ca[ks][f] = *reinterpret_cast<const bfrag*>(
                    zs + (size_t)(rbase + f * 16 + lr) * 128 + ks * 32 + lk * 8);
    }
    asm volatile("s_waitcnt vmcnt(0)" ::: "memory");       // drain ca: clean vmcnt base

    // stage streamed tile t into buf[slot]: 1024 x 16B chunks, 4 per thread.
    // LDS linear; global source pre-swizzled: LDS (r, cpos) holds chunk cpos^(r&7).
    auto STAGE = [&](int t, int slot) {
        const int srow = ((c + d0 + t) & 127) * 64;
        #pragma unroll
        for (int q = 0; q < 4; ++q) {
            const int cbase = q * 256 + wid * 64;          // wave-uniform
            const int chunk = cbase + lane;                // 0..1023
            const int r = chunk >> 4;
            const int cpos = chunk & 15;
            const int csrc = cpos ^ (r & 7);
            const short* g = zs + (size_t)(srow + r) * 128 + csrc * 8;
            __builtin_amdgcn_global_load_lds(
                (const __attribute__((address_space(1))) void*)g,
                (__attribute__((address_space(3))) void*)(
                    &buf[slot][0][0] + (size_t)cbase * 8),
                16, 0, 0);
        }
    };

    STAGE(0, 0);

    constexpr float K_E = 2.8853900817779268f;             // 2 * log2(e)
    float jp[8] = {0.f, 0.f, 0.f, 0.f, 0.f, 0.f, 0.f, 0.f};

    for (int t = 0; t < T; ++t) {
        const bool more = (t + 1 < T);
        if (more) STAGE(t + 1, (t + 1) & 1);
        // Counted waits: guarantee STAGE(t) complete while leaving the
        // prior iteration's 2 atomic instrs + STAGE(t+1)'s 4 loads in flight.
        if (t == 0) {
            if (more) asm volatile("s_waitcnt vmcnt(4)" ::: "memory");
            else      asm volatile("s_waitcnt vmcnt(0)" ::: "memory");
        } else {
            if (more) asm volatile("s_waitcnt vmcnt(6)" ::: "memory");
            else      asm volatile("s_waitcnt vmcnt(2)" ::: "memory");
        }
        __builtin_amdgcn_s_barrier();

        // ---- compute tile t from buf[t&1] ----
        const int sb = ((c + d0 + t) & 127) * 64;          // streamed base row (i side)
        f32x4 acc[2][2] = {};                              // [fj][fi]
        #pragma unroll
        for (int ks = 0; ks < 4; ++ks) {
            bfrag cb[2];
            #pragma unroll
            for (int f = 0; f < 2; ++f) {
                const int r = wi * 32 + f * 16 + lr;
                const int cc = (ks * 4 + lk) ^ (lr & 7);   // swizzled chunk index
                cb[f] = *reinterpret_cast<const bfrag*>(&buf[t & 1][r][cc * 8]);
            }
            #pragma unroll
            for (int fj = 0; fj < 2; ++fj)
                #pragma unroll
                for (int fi = 0; fi < 2; ++fi)
                    acc[fj][fi] = __builtin_amdgcn_mfma_f32_16x16x32_bf16(
                        ca[ks][fj], cb[fi], acc[fj][fi], 0, 0, 0);
        }

        const float cw = (d0 + t) ? 1.f : 0.f;             // self-tile: no col weight
        #pragma unroll
        for (int fi = 0; fi < 2; ++fi) {
            float s = 0.f;
            #pragma unroll
            for (int fj = 0; fj < 2; ++fj)
                #pragma unroll
                for (int r = 0; r < 4; ++r) {
                    const float e = exp2f(acc[fj][fi][r] * K_E);
                    s += e;
                    jp[fj * 4 + r] += e * cw;              // j-col partial (reg, whole strip)
                }
            s += __shfl_xor(s, 16);                        // i-row sum over lk groups
            s += __shfl_xor(s, 32);
            if (lk == 0) atomicAdd(&sumexp[sb + wi * 32 + fi * 16 + lr], s);
        }
        __builtin_amdgcn_s_barrier();                      // all waves done with buf[t&1]
    }

    // ---- once per block: reduce j-col partials over 16 lr lanes ----
    float myv = 0.f;
    #pragma unroll
    for (int tt = 0; tt < 8; ++tt) {
        float v = jp[tt];
        v += __shfl_xor(v, 1);
        v += __shfl_xor(v, 2);
        v += __shfl_xor(v, 4);
        v += __shfl_xor(v, 8);
        if (lr == tt) myv = v;                             // designated writer
    }
    if (lr < 8)
        atomicAdd(&sumexp[c * 64 + wj * 32 + (lr >> 2) * 16 + lk * 4 + (lr & 3)], myv);

    // ---- last-block finalize ----
    __threadfence();                                       // drain + make my atomics visible
    __syncthreads();
    if (tid == 0) {
        int v = __hip_atomic_fetch_add(done, 1, __ATOMIC_ACQ_REL,
                                       __HIP_MEMORY_SCOPE_AGENT);
        lastFlag = (v == NACTIVE - 1);
    }
    __syncthreads();
    if (!lastFlag) return;

    __threadfence();                                       // acquire all blocks' atomics
    constexpr int N = 8192;
    float s = 0.f;
    for (int i = tid; i < N; i += 256) {
        float se = __hip_atomic_load(&sumexp[i], __ATOMIC_RELAXED,
                                     __HIP_MEMORY_SCOPE_AGENT);
        s += __logf(se - exp2f(diag[i] * K_E)) - pos[i];
    }
    #pragma unroll
    for (int m = 32; m; m >>= 1) s += __shfl_xor(s, m);
    if (lane == 0) red[wid] = s;
    __syncthreads();
    if (tid == 0)
        out[0] = (red[0] + red[1] + red[2] + red[3]) * (1.0f / (float)N);
}

extern "C" void kernel_launch(void* const* d_in, const int* in_sizes, int n_in,
                              void* d_out, int out_size, void* d_ws, size_t ws_size,
                              hipStream_t stream) {
    const float* zi = (const float*)d_in[0];
    const float* zj = (const float*)d_in[1];
    float* out = (float*)d_out;

    char* ws = (char*)d_ws;
    unsigned short* zn = (unsigned short*)ws;                    // 2 MB
    float* sumexp = (float*)(ws + 2 * 1024 * 1024);              // 32 KB
    float* diag   = (float*)(ws + 2 * 1024 * 1024 + 1 * 32768);  // 32 KB
    float* pos    = (float*)(ws + 2 * 1024 * 1024 + 2 * 32768);  // 32 KB
    int*   done   = (int*)  (ws + 2 * 1024 * 1024 + 3 * 32768);  // 4 B

    nt_norm_pair<<<1024, 256, 0, stream>>>(zi, zj, zn, diag, pos, sumexp, done);
    nt_gram_sym<<<dim3(128, 9), 256, 0, stream>>>(zn, sumexp, diag, pos, done, out);
}

// Round 8
// 35.997 us; speedup vs baseline: 3.2436x; 3.2436x over previous
//
#include <hip/hip_runtime.h>
#include <hip/hip_bf16.h>

// NT-Xent (SimCLR) loss: B=4096, D=128, N=8192, TEMP=0.5.
// Round 8: revert round-7's fused finalize (per-block __threadfence = L2
// writeback, serialized chip-wide -> 113us). Back to round-6 structure
// (T=4 strips, 2112 blocks, separate finalize kernel), keeping ONE round-7
// change: counted vmcnt that excludes epilogue atomics from the stage wait
// (vmcnt(6) steady-state / vmcnt(2) last tile).

typedef short bfrag __attribute__((ext_vector_type(8)));   // 8 bf16 (4 VGPRs)
typedef float f32x4 __attribute__((ext_vector_type(4)));

static __device__ __forceinline__ unsigned short f2bf_rne(float x) {
    unsigned u = __float_as_uint(x);
    return (unsigned short)((u + 0x7fffu + ((u >> 16) & 1u)) >> 16);
}
static __device__ __forceinline__ float bf2f(unsigned short b) {
    return __uint_as_float(((unsigned)b) << 16);
}

// ------ kernel 1: normalize pair (i, i+B); emit zn/bf16, diag, pos; zero sumexp
__global__ __launch_bounds__(256) void nt_norm_pair(
        const float* __restrict__ zi, const float* __restrict__ zj,
        unsigned short* __restrict__ zn, float* __restrict__ diag,
        float* __restrict__ pos, float* __restrict__ sumexp) {
    constexpr int B = 4096, D = 128;
    const int wave = threadIdx.x >> 6, lane = threadIdx.x & 63;
    const int p = blockIdx.x * 4 + wave;                   // 0..4095
    float2 a = reinterpret_cast<const float2*>(zi + (size_t)p * D)[lane];
    float2 b = reinterpret_cast<const float2*>(zj + (size_t)p * D)[lane];
    float sa = a.x * a.x + a.y * a.y;
    float sb = b.x * b.x + b.y * b.y;
    #pragma unroll
    for (int m = 32; m; m >>= 1) { sa += __shfl_xor(sa, m); sb += __shfl_xor(sb, m); }
    float ia = 1.f / fmaxf(sqrtf(sa), 1e-8f);
    float ib = 1.f / fmaxf(sqrtf(sb), 1e-8f);
    unsigned short a0 = f2bf_rne(a.x * ia), a1 = f2bf_rne(a.y * ia);
    unsigned short b0 = f2bf_rne(b.x * ib), b1 = f2bf_rne(b.y * ib);
    float fa0 = bf2f(a0), fa1 = bf2f(a1), fb0 = bf2f(b0), fb1 = bf2f(b1);
    float da = fa0 * fa0 + fa1 * fa1;                      // bf16 self-dot (matches MFMA diag)
    float db = fb0 * fb0 + fb1 * fb1;
    float cr = fa0 * fb0 + fa1 * fb1;                      // bf16 cross-dot (positive pair)
    #pragma unroll
    for (int m = 32; m; m >>= 1) {
        da += __shfl_xor(da, m); db += __shfl_xor(db, m); cr += __shfl_xor(cr, m);
    }
    reinterpret_cast<unsigned*>(zn + (size_t)p * D)[lane] =
        (unsigned)a0 | ((unsigned)a1 << 16);
    reinterpret_cast<unsigned*>(zn + (size_t)(p + B) * D)[lane] =
        (unsigned)b0 | ((unsigned)b1 << 16);
    if (lane == 0) {
        diag[p] = da; diag[p + B] = db;
        pos[p] = 2.f * cr; pos[p + B] = 2.f * cr;          // sim symmetric
        sumexp[p] = 0.f; sumexp[p + B] = 0.f;              // replaces hipMemsetAsync
    }
}

// ------ kernel 2: strip-mined symmetric gram ------------------------------
// grid (128, 17): cached tile c = blockIdx.x; y<16: streamed tiles at
// d = 4y+t (t=0..3); y==16 (c<64 only): single tile d=64. Each unordered
// tile pair exactly once. acc[fj][fi] = sim[j in cached][i in streamed].
__global__ __launch_bounds__(256, 4) void nt_gram_sym(
        const unsigned short* __restrict__ zn, float* __restrict__ sumexp) {
    const int c = blockIdx.x;
    const int y = blockIdx.y;
    if (y == 16 && c >= 64) return;
    const int T  = (y == 16) ? 1 : 4;
    const int d0 = (y == 16) ? 64 : 4 * y;

    __shared__ short buf[2][64][128];                      // 2 x 16 KB stream buffers

    const short* zs = (const short*)zn;
    const int tid = threadIdx.x, wid = tid >> 6, lane = tid & 63;
    const int wj = wid >> 1, wi = wid & 1;                 // wave quadrant
    const int lr = lane & 15, lk = lane >> 4;

    // cached A-frags (tile c, this wave's 32 j-rows), direct from L2
    bfrag ca[4][2];
    {
        const int rbase = c * 64 + wj * 32;
        #pragma unroll
        for (int ks = 0; ks < 4; ++ks)
            #pragma unroll
            for (int f = 0; f < 2; ++f)
                ca[ks][f] = *reinterpret_cast<const bfrag*>(
                    zs + (size_t)(rbase + f * 16 + lr) * 128 + ks * 32 + lk * 8);
    }
    asm volatile("s_waitcnt vmcnt(0)" ::: "memory");       // drain ca: clean vmcnt base

    // stage streamed tile t into buf[slot]: 1024 x 16B chunks, 4 per thread.
    // LDS linear; global source pre-swizzled: LDS (r, cpos) holds chunk cpos^(r&7).
    auto STAGE = [&](int t, int slot) {
        const int srow = ((c + d0 + t) & 127) * 64;
        #pragma unroll
        for (int q = 0; q < 4; ++q) {
            const int cbase = q * 256 + wid * 64;          // wave-uniform
            const int chunk = cbase + lane;                // 0..1023
            const int r = chunk >> 4;
            const int cpos = chunk & 15;
            const int csrc = cpos ^ (r & 7);
            const short* g = zs + (size_t)(srow + r) * 128 + csrc * 8;
            __builtin_amdgcn_global_load_lds(
                (const __attribute__((address_space(1))) void*)g,
                (__attribute__((address_space(3))) void*)(
                    &buf[slot][0][0] + (size_t)cbase * 8),
                16, 0, 0);
        }
    };

    STAGE(0, 0);

    constexpr float K_E = 2.8853900817779268f;             // 2 * log2(e)
    float jp[8] = {0.f, 0.f, 0.f, 0.f, 0.f, 0.f, 0.f, 0.f};

    for (int t = 0; t < T; ++t) {
        const bool more = (t + 1 < T);
        if (more) STAGE(t + 1, (t + 1) & 1);
        // Counted waits: STAGE(t) complete; prior iteration's 2 atomic
        // instrs + STAGE(t+1)'s 4 loads stay in flight (never drain atomics
        // mid-loop -- that was round 6's hidden per-tile serial cost).
        if (t == 0) {
            if (more) asm volatile("s_waitcnt vmcnt(4)" ::: "memory");
            else      asm volatile("s_waitcnt vmcnt(0)" ::: "memory");
        } else {
            if (more) asm volatile("s_waitcnt vmcnt(6)" ::: "memory");
            else      asm volatile("s_waitcnt vmcnt(2)" ::: "memory");
        }
        __builtin_amdgcn_s_barrier();

        // ---- compute tile t from buf[t&1] ----
        const int sb = ((c + d0 + t) & 127) * 64;          // streamed base row (i side)
        f32x4 acc[2][2] = {};                              // [fj][fi]
        #pragma unroll
        for (int ks = 0; ks < 4; ++ks) {
            bfrag cb[2];
            #pragma unroll
            for (int f = 0; f < 2; ++f) {
                const int r = wi * 32 + f * 16 + lr;
                const int cc = (ks * 4 + lk) ^ (lr & 7);   // swizzled chunk index
                cb[f] = *reinterpret_cast<const bfrag*>(&buf[t & 1][r][cc * 8]);
            }
            #pragma unroll
            for (int fj = 0; fj < 2; ++fj)
                #pragma unroll
                for (int fi = 0; fi < 2; ++fi)
                    acc[fj][fi] = __builtin_amdgcn_mfma_f32_16x16x32_bf16(
                        ca[ks][fj], cb[fi], acc[fj][fi], 0, 0, 0);
        }

        const float cw = (d0 + t) ? 1.f : 0.f;             // self-tile: no col weight
        #pragma unroll
        for (int fi = 0; fi < 2; ++fi) {
            float s = 0.f;
            #pragma unroll
            for (int fj = 0; fj < 2; ++fj)
                #pragma unroll
                for (int r = 0; r < 4; ++r) {
                    const float e = exp2f(acc[fj][fi][r] * K_E);
                    s += e;
                    jp[fj * 4 + r] += e * cw;              // j-col partial (reg, whole strip)
                }
            s += __shfl_xor(s, 16);                        // i-row sum over lk groups
            s += __shfl_xor(s, 32);
            if (lk == 0) atomicAdd(&sumexp[sb + wi * 32 + fi * 16 + lr], s);
        }
        __builtin_amdgcn_s_barrier();                      // all waves done with buf[t&1]
    }

    // ---- once per block: reduce j-col partials over 16 lr lanes ----
    float myv = 0.f;
    #pragma unroll
    for (int tt = 0; tt < 8; ++tt) {
        float v = jp[tt];
        v += __shfl_xor(v, 1);
        v += __shfl_xor(v, 2);
        v += __shfl_xor(v, 4);
        v += __shfl_xor(v, 8);
        if (lr == tt) myv = v;                             // designated writer
    }
    if (lr < 8)
        atomicAdd(&sumexp[c * 64 + wj * 32 + (lr >> 2) * 16 + lk * 4 + (lr & 3)], myv);
}

// ------ kernel 3: finalize scalar ------------------------------------------
__global__ __launch_bounds__(1024) void nt_finalize(
        const float* __restrict__ sumexp, const float* __restrict__ diag,
        const float* __restrict__ pos, float* __restrict__ out) {
    constexpr int N = 8192;
    constexpr float K_E = 2.8853900817779268f;
    float s = 0.f;
    for (int i = threadIdx.x; i < N; i += 1024)
        s += __logf(sumexp[i] - exp2f(diag[i] * K_E)) - pos[i];
    #pragma unroll
    for (int m = 32; m; m >>= 1) s += __shfl_xor(s, m);
    __shared__ float red[16];
    if ((threadIdx.x & 63) == 0) red[threadIdx.x >> 6] = s;
    __syncthreads();
    if (threadIdx.x == 0) {
        float t = 0.f;
        #pragma unroll
        for (int w = 0; w < 16; ++w) t += red[w];
        out[0] = t * (1.0f / (float)N);
    }
}

extern "C" void kernel_launch(void* const* d_in, const int* in_sizes, int n_in,
                              void* d_out, int out_size, void* d_ws, size_t ws_size,
                              hipStream_t stream) {
    const float* zi = (const float*)d_in[0];
    const float* zj = (const float*)d_in[1];
    float* out = (float*)d_out;

    char* ws = (char*)d_ws;
    unsigned short* zn = (unsigned short*)ws;                    // 2 MB
    float* sumexp = (float*)(ws + 2 * 1024 * 1024);              // 32 KB
    float* diag   = (float*)(ws + 2 * 1024 * 1024 + 1 * 32768);  // 32 KB
    float* pos    = (float*)(ws + 2 * 1024 * 1024 + 2 * 32768);  // 32 KB

    nt_norm_pair<<<1024, 256, 0, stream>>>(zi, zj, zn, diag, pos, sumexp);
    nt_gram_sym<<<dim3(128, 17), 256, 0, stream>>>(zn, sumexp);
    nt_finalize<<<1, 1024, 0, stream>>>(sumexp, diag, pos, out);
}